// Round 2
// baseline (370.800 us; speedup 1.0000x reference)
//
#include <hip/hip_runtime.h>
#include <math.h>

#define DD 256
#define HH 4
#define HDIM 64
#define LN_EPS 1e-5f

// ---------------- CSR build ----------------

__global__ void k_zero(int* __restrict__ p, int n) {
    int i = blockIdx.x * 256 + threadIdx.x;
    if (i < n) p[i] = 0;
}

__global__ void k_count(const int* __restrict__ dst, int E_, int* __restrict__ deg) {
    int e = blockIdx.x * 256 + threadIdx.x;
    if (e < E_) atomicAdd(&deg[dst[e]], 1);
}

// single block, 1024 threads; assumes N_ <= 16384
__global__ void __launch_bounds__(1024) k_scan(const int* __restrict__ deg, int N_,
                                               int* __restrict__ offs, int* __restrict__ cursor) {
    __shared__ int part[1024];
    int t = threadIdx.x;
    int items = (N_ + 1023) >> 10;
    if (items > 16) items = 16;
    int base = t * items;
    int loc[16];
    int s = 0;
    for (int i = 0; i < items; i++) {
        int idx = base + i;
        int d = (idx < N_) ? deg[idx] : 0;
        loc[i] = s;
        s += d;
    }
    part[t] = s;
    __syncthreads();
    for (int off = 1; off < 1024; off <<= 1) {
        int v = (t >= off) ? part[t - off] : 0;
        __syncthreads();
        part[t] += v;
        __syncthreads();
    }
    int excl = (t > 0) ? part[t - 1] : 0;
    for (int i = 0; i < items; i++) {
        int idx = base + i;
        if (idx < N_) {
            offs[idx] = excl + loc[i];
            cursor[idx] = 0;
        }
    }
    if (t == 0) offs[N_] = part[1023];
}

__global__ void k_fill(const int* __restrict__ src, const int* __restrict__ dst, int E_,
                       const int* __restrict__ offs, int* __restrict__ cursor,
                       int* __restrict__ csr) {
    int e = blockIdx.x * 256 + threadIdx.x;
    if (e >= E_) return;
    int d = dst[e];
    int p = atomicAdd(&cursor[d], 1);
    csr[offs[d] + p] = src[e];
}

// ---------------- block-wide float4 reduction (256 threads) ----------------

__device__ __forceinline__ float4 blockReduce4(float4 v, float4* red) {
    int t = threadIdx.x;
    red[t] = v;
    __syncthreads();
#pragma unroll
    for (int s = 128; s > 0; s >>= 1) {
        if (t < s) {
            float4 a = red[t], b = red[t + s];
            red[t] = make_float4(a.x + b.x, a.y + b.y, a.z + b.z, a.w + b.w);
        }
        __syncthreads();
    }
    float4 r = red[0];
    __syncthreads();
    return r;
}

// ---------------- LN1 + Q/K/V projection (4 nodes per block) ----------------

__global__ void __launch_bounds__(256) k_ln_qkv(
    const float* __restrict__ x, const float* __restrict__ g1, const float* __restrict__ b1,
    const float* __restrict__ Wq, const float* __restrict__ bq,
    const float* __restrict__ Wk, const float* __restrict__ bk,
    const float* __restrict__ Wv, const float* __restrict__ bv,
    int N_, float* __restrict__ q, float* __restrict__ k, float* __restrict__ v) {
    __shared__ float xn[4][DD];
    __shared__ float4 red[256];
    int t = threadIdx.x;
    int n0 = blockIdx.x * 4;

    float val[4];
#pragma unroll
    for (int r = 0; r < 4; r++) {
        int n = n0 + r;
        val[r] = (n < N_) ? x[n * DD + t] : 0.f;
    }
    float4 s1 = blockReduce4(make_float4(val[0], val[1], val[2], val[3]), red);
    float mean[4] = {s1.x * (1.f / DD), s1.y * (1.f / DD), s1.z * (1.f / DD), s1.w * (1.f / DD)};
    float dv[4];
#pragma unroll
    for (int r = 0; r < 4; r++) dv[r] = val[r] - mean[r];
    float4 s2 = blockReduce4(make_float4(dv[0] * dv[0], dv[1] * dv[1], dv[2] * dv[2], dv[3] * dv[3]), red);
    float rstd[4] = {rsqrtf(s2.x * (1.f / DD) + LN_EPS), rsqrtf(s2.y * (1.f / DD) + LN_EPS),
                     rsqrtf(s2.z * (1.f / DD) + LN_EPS), rsqrtf(s2.w * (1.f / DD) + LN_EPS)};
    float gv = g1[t], bv1 = b1[t];
#pragma unroll
    for (int r = 0; r < 4; r++) xn[r][t] = dv[r] * rstd[r] * gv + bv1;
    __syncthreads();

    float aq[4], ak[4], av[4];
    float bqv = bq[t], bkv = bk[t], bvv = bv[t];
#pragma unroll
    for (int r = 0; r < 4; r++) { aq[r] = bqv; ak[r] = bkv; av[r] = bvv; }

    for (int i = 0; i < DD; i++) {
        float wq = Wq[i * DD + t];
        float wk = Wk[i * DD + t];
        float wv = Wv[i * DD + t];
#pragma unroll
        for (int r = 0; r < 4; r++) {
            float xv = xn[r][i];
            aq[r] += xv * wq;
            ak[r] += xv * wk;
            av[r] += xv * wv;
        }
    }
#pragma unroll
    for (int r = 0; r < 4; r++) {
        int n = n0 + r;
        if (n < N_) {
            q[n * DD + t] = aq[r] * 0.125f;  // fold 1/sqrt(HD)
            k[n * DD + t] = ak[r];
            v[n * DD + t] = av[r];
        }
    }
}

// ---------------- per-destination-node online-softmax attention ----------------
// block = 256 threads = 4 waves; wave h handles head h; lane = dim within head.

__global__ void __launch_bounds__(256) k_attn(
    const float* __restrict__ q, const float* __restrict__ k, const float* __restrict__ v,
    const int* __restrict__ offs, const int* __restrict__ csr,
    float* __restrict__ agg) {
    int node = blockIdx.x;
    int t = threadIdx.x;
    int lane = t & 63;
    int h = t >> 6;
    int col = h * HDIM + lane;

    float qv = q[node * DD + col];
    int e0 = offs[node], e1 = offs[node + 1];

    float m = -INFINITY, l = 0.f, acc = 0.f;
    for (int e = e0; e < e1; e++) {
        int src = csr[e];
        float kv = k[src * DD + col];
        float s = qv * kv;
#pragma unroll
        for (int o = 32; o > 0; o >>= 1) s += __shfl_xor(s, o);
        float mn = fmaxf(m, s);
        float p = __expf(s - mn);
        float sc = __expf(m - mn);  // 0 on first iter (m = -inf)
        float vv = v[src * DD + col];
        l = l * sc + p;
        acc = acc * sc + p * vv;
        m = mn;
    }
    agg[node * DD + col] = (e1 > e0) ? (acc / l) : 0.f;
}

// ---------------- output GEMM + LN2 + relu + residual (4 nodes per block) ----------------

__global__ void __launch_bounds__(256) k_out(
    const float* __restrict__ agg, const float* __restrict__ Wo, const float* __restrict__ bo,
    const float* __restrict__ g2, const float* __restrict__ b2,
    const float* __restrict__ x, int N_, float* __restrict__ out) {
    __shared__ float ag[4][DD];
    __shared__ float4 red[256];
    int t = threadIdx.x;
    int n0 = blockIdx.x * 4;

#pragma unroll
    for (int r = 0; r < 4; r++) {
        int n = n0 + r;
        ag[r][t] = (n < N_) ? agg[n * DD + t] : 0.f;
    }
    __syncthreads();

    float a[4];
    float bov = bo[t];
#pragma unroll
    for (int r = 0; r < 4; r++) a[r] = bov;
    for (int i = 0; i < DD; i++) {
        float w = Wo[i * DD + t];
#pragma unroll
        for (int r = 0; r < 4; r++) a[r] += ag[r][i] * w;
    }

    float4 s1 = blockReduce4(make_float4(a[0], a[1], a[2], a[3]), red);
    float mean[4] = {s1.x * (1.f / DD), s1.y * (1.f / DD), s1.z * (1.f / DD), s1.w * (1.f / DD)};
    float dv[4];
#pragma unroll
    for (int r = 0; r < 4; r++) dv[r] = a[r] - mean[r];
    float4 s2 = blockReduce4(make_float4(dv[0] * dv[0], dv[1] * dv[1], dv[2] * dv[2], dv[3] * dv[3]), red);
    float rstd[4] = {rsqrtf(s2.x * (1.f / DD) + LN_EPS), rsqrtf(s2.y * (1.f / DD) + LN_EPS),
                     rsqrtf(s2.z * (1.f / DD) + LN_EPS), rsqrtf(s2.w * (1.f / DD) + LN_EPS)};
    float gv = g2[t], bbv = b2[t];
#pragma unroll
    for (int r = 0; r < 4; r++) {
        int n = n0 + r;
        if (n < N_) {
            float y = dv[r] * rstd[r] * gv + bbv;
            y = fmaxf(y, 0.f);
            out[n * DD + t] = x[n * DD + t] + y;
        }
    }
}

// ---------------- launch ----------------

extern "C" void kernel_launch(void* const* d_in, const int* in_sizes, int n_in,
                              void* d_out, int out_size, void* d_ws, size_t ws_size,
                              hipStream_t stream) {
    const float* x  = (const float*)d_in[0];
    const int*   ei = (const int*)d_in[1];
    const float* g1 = (const float*)d_in[2];
    const float* b1 = (const float*)d_in[3];
    const float* g2 = (const float*)d_in[4];
    const float* b2 = (const float*)d_in[5];
    const float* Wq = (const float*)d_in[6];
    const float* bq = (const float*)d_in[7];
    const float* Wk = (const float*)d_in[8];
    const float* bk = (const float*)d_in[9];
    const float* Wv = (const float*)d_in[10];
    const float* bv = (const float*)d_in[11];
    const float* Wo = (const float*)d_in[12];
    const float* bo = (const float*)d_in[13];
    float* out = (float*)d_out;

    int N_ = in_sizes[0] / DD;
    int E_ = in_sizes[1] / 2;
    const int* srcp = ei;
    const int* dstp = ei + E_;

    char* w = (char*)d_ws;
    float* q   = (float*)w; w += (size_t)N_ * DD * 4;
    float* k   = (float*)w; w += (size_t)N_ * DD * 4;
    float* v   = (float*)w; w += (size_t)N_ * DD * 4;
    float* agg = (float*)w; w += (size_t)N_ * DD * 4;
    int* deg    = (int*)w;  w += (size_t)N_ * 4;
    int* offs   = (int*)w;  w += (size_t)(N_ + 1) * 4;
    int* cursor = (int*)w;  w += (size_t)N_ * 4;
    int* csr    = (int*)w;  w += (size_t)E_ * 4;

    k_zero<<<(N_ + 255) / 256, 256, 0, stream>>>(deg, N_);
    k_count<<<(E_ + 255) / 256, 256, 0, stream>>>(dstp, E_, deg);
    k_scan<<<1, 1024, 0, stream>>>(deg, N_, offs, cursor);
    k_fill<<<(E_ + 255) / 256, 256, 0, stream>>>(srcp, dstp, E_, offs, cursor, csr);
    k_ln_qkv<<<(N_ + 3) / 4, 256, 0, stream>>>(x, g1, b1, Wq, bq, Wk, bk, Wv, bv,
                                               N_, q, k, v);
    k_attn<<<N_, 256, 0, stream>>>(q, k, v, offs, csr, agg);
    k_out<<<(N_ + 3) / 4, 256, 0, stream>>>(agg, Wo, bo, g2, b2, x, N_, out);
}

// Round 3
// 346.857 us; speedup vs baseline: 1.0690x; 1.0690x over previous
//
#include <hip/hip_runtime.h>
#include <math.h>

#define DD 256
#define HH 4
#define HDIM 64
#define LN_EPS 1e-5f
#define NB 16   // nodes per GEMM block

// ---------------- CSR build ----------------

__global__ void k_zero(int* __restrict__ p, int n) {
    int i = blockIdx.x * 256 + threadIdx.x;
    if (i < n) p[i] = 0;
}

__global__ void k_count(const int* __restrict__ dst, int E_, int* __restrict__ deg) {
    int e = blockIdx.x * 256 + threadIdx.x;
    if (e < E_) atomicAdd(&deg[dst[e]], 1);
}

__global__ void __launch_bounds__(1024) k_scan(const int* __restrict__ deg, int N_,
                                               int* __restrict__ offs, int* __restrict__ cursor) {
    __shared__ int part[1024];
    int t = threadIdx.x;
    int items = (N_ + 1023) >> 10;
    if (items > 16) items = 16;
    int base = t * items;
    int loc[16];
    int s = 0;
    for (int i = 0; i < items; i++) {
        int idx = base + i;
        int d = (idx < N_) ? deg[idx] : 0;
        loc[i] = s;
        s += d;
    }
    part[t] = s;
    __syncthreads();
    for (int off = 1; off < 1024; off <<= 1) {
        int v = (t >= off) ? part[t - off] : 0;
        __syncthreads();
        part[t] += v;
        __syncthreads();
    }
    int excl = (t > 0) ? part[t - 1] : 0;
    for (int i = 0; i < items; i++) {
        int idx = base + i;
        if (idx < N_) {
            offs[idx] = excl + loc[i];
            cursor[idx] = 0;
        }
    }
    if (t == 0) offs[N_] = part[1023];
}

__global__ void k_fill(const int* __restrict__ src, const int* __restrict__ dst, int E_,
                       const int* __restrict__ offs, int* __restrict__ cursor,
                       int* __restrict__ csr) {
    int e = blockIdx.x * 256 + threadIdx.x;
    if (e >= E_) return;
    int d = dst[e];
    int p = atomicAdd(&cursor[d], 1);
    csr[offs[d] + p] = src[e];
}

// ---------------- fused LN1 + Q/K/V projection, 16 nodes per block ----------------

__global__ void __launch_bounds__(256) k_qkv(
    const float* __restrict__ x, const float* __restrict__ g1, const float* __restrict__ b1,
    const float* __restrict__ Wq, const float* __restrict__ bq,
    const float* __restrict__ Wk, const float* __restrict__ bk,
    const float* __restrict__ Wv, const float* __restrict__ bv,
    int N_, float* __restrict__ q, float* __restrict__ k, float* __restrict__ v) {
    __shared__ float xs[NB][DD];
    __shared__ float wp[4][NB];
    int t = threadIdx.x;
    int n0 = blockIdx.x * NB;
    int wv_ = t >> 6, ln_ = t & 63;

    // load x tile (flat float4)
#pragma unroll
    for (int it = 0; it < NB / 4; it++) {
        int flat = it * 256 + t;
        int row = flat >> 6;
        int col4 = (flat & 63) << 2;
        int n = n0 + row;
        float4 val = make_float4(0.f, 0.f, 0.f, 0.f);
        if (n < N_) val = *(const float4*)&x[(size_t)n * DD + col4];
        *(float4*)&xs[row][col4] = val;
    }
    __syncthreads();

    // LayerNorm across columns; thread t owns column t of every row
    float xv[NB];
#pragma unroll
    for (int r = 0; r < NB; r++) xv[r] = xs[r][t];

    float mean[NB], rstd[NB];
#pragma unroll
    for (int r = 0; r < NB; r++) {
        float s = xv[r];
        s += __shfl_xor(s, 1); s += __shfl_xor(s, 2); s += __shfl_xor(s, 4);
        s += __shfl_xor(s, 8); s += __shfl_xor(s, 16); s += __shfl_xor(s, 32);
        if (ln_ == 0) wp[wv_][r] = s;
    }
    __syncthreads();
#pragma unroll
    for (int r = 0; r < NB; r++)
        mean[r] = (wp[0][r] + wp[1][r] + wp[2][r] + wp[3][r]) * (1.f / DD);
    __syncthreads();
#pragma unroll
    for (int r = 0; r < NB; r++) {
        float d = xv[r] - mean[r];
        float s = d * d;
        s += __shfl_xor(s, 1); s += __shfl_xor(s, 2); s += __shfl_xor(s, 4);
        s += __shfl_xor(s, 8); s += __shfl_xor(s, 16); s += __shfl_xor(s, 32);
        if (ln_ == 0) wp[wv_][r] = s;
    }
    __syncthreads();
#pragma unroll
    for (int r = 0; r < NB; r++)
        rstd[r] = rsqrtf((wp[0][r] + wp[1][r] + wp[2][r] + wp[3][r]) * (1.f / DD) + LN_EPS);
    float gv = g1[t], bv1 = b1[t];
    __syncthreads();
#pragma unroll
    for (int r = 0; r < NB; r++) xs[r][t] = (xv[r] - mean[r]) * rstd[r] * gv + bv1;
    __syncthreads();

    // GEMM: 48 FMA per i, weights read once per block
    float aq[NB], ak[NB], av[NB];
    float bqv = bq[t], bkv = bk[t], bvv = bv[t];
#pragma unroll
    for (int r = 0; r < NB; r++) { aq[r] = bqv; ak[r] = bkv; av[r] = bvv; }

#pragma unroll 4
    for (int i = 0; i < DD; i++) {
        float wq = Wq[i * DD + t];
        float wk = Wk[i * DD + t];
        float wvv = Wv[i * DD + t];
#pragma unroll
        for (int r = 0; r < NB; r++) {
            float xn = xs[r][i];
            aq[r] = fmaf(xn, wq, aq[r]);
            ak[r] = fmaf(xn, wk, ak[r]);
            av[r] = fmaf(xn, wvv, av[r]);
        }
    }
#pragma unroll
    for (int r = 0; r < NB; r++) {
        int n = n0 + r;
        if (n < N_) {
            q[(size_t)n * DD + t] = aq[r] * 0.125f;  // fold 1/sqrt(HD)
            k[(size_t)n * DD + t] = ak[r];
            v[(size_t)n * DD + t] = av[r];
        }
    }
}

// ---------------- attention: 4 waves = 4 heads; 16 lanes/edge x 4 edges/wave ----------------

__global__ void __launch_bounds__(256) k_attn(
    const float* __restrict__ q, const float* __restrict__ k, const float* __restrict__ v,
    const int* __restrict__ offs, const int* __restrict__ csr,
    float* __restrict__ agg) {
    int node = blockIdx.x;
    int t = threadIdx.x;
    int h = t >> 6;
    int lane = t & 63;
    int g = lane >> 4;       // edge subgroup 0..3
    int li = lane & 15;      // 4 dims per lane
    int colb = h * HDIM + (li << 2);

    int e0 = offs[node], e1 = offs[node + 1];
    if (e0 == e1) {
        if (g == 0) *(float4*)&agg[(size_t)node * DD + colb] = make_float4(0.f, 0.f, 0.f, 0.f);
        return;
    }

    float4 qv = *(const float4*)&q[(size_t)node * DD + colb];
    float m = -INFINITY, l = 0.f;
    float ax = 0.f, ay = 0.f, az = 0.f, aw = 0.f;

    for (int e = e0; e < e1; e += 4) {
        int ee = e + g;
        bool valid = ee < e1;
        int src = csr[valid ? ee : e0];
        size_t base = (size_t)src * DD + colb;
        float4 kv = *(const float4*)&k[base];
        float4 vv = *(const float4*)&v[base];
        float s = qv.x * kv.x + qv.y * kv.y + qv.z * kv.z + qv.w * kv.w;
        s += __shfl_xor(s, 1); s += __shfl_xor(s, 2);
        s += __shfl_xor(s, 4); s += __shfl_xor(s, 8);
        if (!valid) s = -INFINITY;
        float smax = fmaxf(s, __shfl_xor(s, 16));
        smax = fmaxf(smax, __shfl_xor(smax, 32));
        float mn = fmaxf(m, smax);
        float p = __expf(s - mn);        // 0 for invalid groups
        float sc = __expf(m - mn);       // 0 on first iteration
        float ps = p + __shfl_xor(p, 16);
        ps += __shfl_xor(ps, 32);
        l = l * sc + ps;
        ax = ax * sc + p * vv.x;
        ay = ay * sc + p * vv.y;
        az = az * sc + p * vv.z;
        aw = aw * sc + p * vv.w;
        m = mn;
    }
    // sum partial accumulators across the 4 edge-subgroups
    ax += __shfl_xor(ax, 16); ax += __shfl_xor(ax, 32);
    ay += __shfl_xor(ay, 16); ay += __shfl_xor(ay, 32);
    az += __shfl_xor(az, 16); az += __shfl_xor(az, 32);
    aw += __shfl_xor(aw, 16); aw += __shfl_xor(aw, 32);
    float invl = 1.f / l;
    if (g == 0) {
        *(float4*)&agg[(size_t)node * DD + colb] =
            make_float4(ax * invl, ay * invl, az * invl, aw * invl);
    }
}

// ---------------- output GEMM + LN2 + relu + residual, 16 nodes per block ----------------

__global__ void __launch_bounds__(256) k_out(
    const float* __restrict__ agg, const float* __restrict__ Wo, const float* __restrict__ bo,
    const float* __restrict__ g2, const float* __restrict__ b2,
    const float* __restrict__ x, int N_, float* __restrict__ out) {
    __shared__ float as[NB][DD];
    __shared__ float wp[4][NB];
    int t = threadIdx.x;
    int n0 = blockIdx.x * NB;
    int wv_ = t >> 6, ln_ = t & 63;

#pragma unroll
    for (int it = 0; it < NB / 4; it++) {
        int flat = it * 256 + t;
        int row = flat >> 6;
        int col4 = (flat & 63) << 2;
        int n = n0 + row;
        float4 val = make_float4(0.f, 0.f, 0.f, 0.f);
        if (n < N_) val = *(const float4*)&agg[(size_t)n * DD + col4];
        *(float4*)&as[row][col4] = val;
    }
    __syncthreads();

    float a[NB];
    float bov = bo[t];
#pragma unroll
    for (int r = 0; r < NB; r++) a[r] = bov;

#pragma unroll 4
    for (int i = 0; i < DD; i++) {
        float w = Wo[i * DD + t];
#pragma unroll
        for (int r = 0; r < NB; r++) a[r] = fmaf(as[r][i], w, a[r]);
    }

    // LN2 across columns
    float mean[NB], rstd[NB];
#pragma unroll
    for (int r = 0; r < NB; r++) {
        float s = a[r];
        s += __shfl_xor(s, 1); s += __shfl_xor(s, 2); s += __shfl_xor(s, 4);
        s += __shfl_xor(s, 8); s += __shfl_xor(s, 16); s += __shfl_xor(s, 32);
        if (ln_ == 0) wp[wv_][r] = s;
    }
    __syncthreads();
#pragma unroll
    for (int r = 0; r < NB; r++)
        mean[r] = (wp[0][r] + wp[1][r] + wp[2][r] + wp[3][r]) * (1.f / DD);
    __syncthreads();
#pragma unroll
    for (int r = 0; r < NB; r++) {
        float d = a[r] - mean[r];
        float s = d * d;
        s += __shfl_xor(s, 1); s += __shfl_xor(s, 2); s += __shfl_xor(s, 4);
        s += __shfl_xor(s, 8); s += __shfl_xor(s, 16); s += __shfl_xor(s, 32);
        if (ln_ == 0) wp[wv_][r] = s;
    }
    __syncthreads();
#pragma unroll
    for (int r = 0; r < NB; r++)
        rstd[r] = rsqrtf((wp[0][r] + wp[1][r] + wp[2][r] + wp[3][r]) * (1.f / DD) + LN_EPS);

    float gv = g2[t], bbv = b2[t];
#pragma unroll
    for (int r = 0; r < NB; r++) {
        int n = n0 + r;
        if (n < N_) {
            float y = (a[r] - mean[r]) * rstd[r] * gv + bbv;
            y = fmaxf(y, 0.f);
            out[(size_t)n * DD + t] = x[(size_t)n * DD + t] + y;
        }
    }
}

// ---------------- launch ----------------

extern "C" void kernel_launch(void* const* d_in, const int* in_sizes, int n_in,
                              void* d_out, int out_size, void* d_ws, size_t ws_size,
                              hipStream_t stream) {
    const float* x  = (const float*)d_in[0];
    const int*   ei = (const int*)d_in[1];
    const float* g1 = (const float*)d_in[2];
    const float* b1 = (const float*)d_in[3];
    const float* g2 = (const float*)d_in[4];
    const float* b2 = (const float*)d_in[5];
    const float* Wq = (const float*)d_in[6];
    const float* bq = (const float*)d_in[7];
    const float* Wk = (const float*)d_in[8];
    const float* bk = (const float*)d_in[9];
    const float* Wv = (const float*)d_in[10];
    const float* bv = (const float*)d_in[11];
    const float* Wo = (const float*)d_in[12];
    const float* bo = (const float*)d_in[13];
    float* out = (float*)d_out;

    int N_ = in_sizes[0] / DD;
    int E_ = in_sizes[1] / 2;
    const int* srcp = ei;
    const int* dstp = ei + E_;

    char* w = (char*)d_ws;
    float* q   = (float*)w; w += (size_t)N_ * DD * 4;
    float* k   = (float*)w; w += (size_t)N_ * DD * 4;
    float* v   = (float*)w; w += (size_t)N_ * DD * 4;
    float* agg = (float*)w; w += (size_t)N_ * DD * 4;
    int* deg    = (int*)w;  w += (size_t)N_ * 4;
    int* offs   = (int*)w;  w += (size_t)(N_ + 1) * 4;
    int* cursor = (int*)w;  w += (size_t)N_ * 4;
    int* csr    = (int*)w;  w += (size_t)E_ * 4;

    k_zero<<<(N_ + 255) / 256, 256, 0, stream>>>(deg, N_);
    k_count<<<(E_ + 255) / 256, 256, 0, stream>>>(dstp, E_, deg);
    k_scan<<<1, 1024, 0, stream>>>(deg, N_, offs, cursor);
    k_fill<<<(E_ + 255) / 256, 256, 0, stream>>>(srcp, dstp, E_, offs, cursor, csr);
    k_qkv<<<(N_ + NB - 1) / NB, 256, 0, stream>>>(x, g1, b1, Wq, bq, Wk, bk, Wv, bv,
                                                  N_, q, k, v);
    k_attn<<<N_, 256, 0, stream>>>(q, k, v, offs, csr, agg);
    k_out<<<(N_ + NB - 1) / NB, 256, 0, stream>>>(agg, Wo, bo, g2, b2, x, N_, out);
}

// Round 4
// 265.372 us; speedup vs baseline: 1.3973x; 1.3071x over previous
//
#include <hip/hip_runtime.h>
#include <hip/hip_bf16.h>
#include <math.h>

#define DD 256
#define LN_EPS 1e-5f

typedef unsigned short u16;
typedef __attribute__((ext_vector_type(8))) short short8;
typedef __attribute__((ext_vector_type(4))) float floatx4;

__device__ __forceinline__ u16 f2b(float f) {
    __hip_bfloat16 h = __float2bfloat16(f);
    return *reinterpret_cast<u16*>(&h);
}
__device__ __forceinline__ float b2f(unsigned int u) {
    union { unsigned int i; float f; } x;
    x.i = u << 16;
    return x.f;
}

// ---------------- CSR build ----------------

__global__ void k_zero(int* __restrict__ p, int n) {
    int i = blockIdx.x * 256 + threadIdx.x;
    if (i < n) p[i] = 0;
}

__global__ void k_count(const int* __restrict__ dst, int E_, int* __restrict__ deg) {
    int e = blockIdx.x * 256 + threadIdx.x;
    if (e < E_) atomicAdd(&deg[dst[e]], 1);
}

__global__ void __launch_bounds__(1024) k_scan(const int* __restrict__ deg, int N_,
                                               int* __restrict__ offs, int* __restrict__ cursor) {
    __shared__ int part[1024];
    int t = threadIdx.x;
    int items = (N_ + 1023) >> 10;
    if (items > 16) items = 16;
    int base = t * items;
    int loc[16];
    int s = 0;
    for (int i = 0; i < items; i++) {
        int idx = base + i;
        int d = (idx < N_) ? deg[idx] : 0;
        loc[i] = s;
        s += d;
    }
    part[t] = s;
    __syncthreads();
    for (int off = 1; off < 1024; off <<= 1) {
        int v = (t >= off) ? part[t - off] : 0;
        __syncthreads();
        part[t] += v;
        __syncthreads();
    }
    int excl = (t > 0) ? part[t - 1] : 0;
    for (int i = 0; i < items; i++) {
        int idx = base + i;
        if (idx < N_) {
            offs[idx] = excl + loc[i];
            cursor[idx] = 0;
        }
    }
    if (t == 0) offs[N_] = part[1023];
}

__global__ void k_fill(const int* __restrict__ src, const int* __restrict__ dst, int E_,
                       const int* __restrict__ offs, int* __restrict__ cursor,
                       int* __restrict__ csr) {
    int e = blockIdx.x * 256 + threadIdx.x;
    if (e >= E_) return;
    int d = dst[e];
    int p = atomicAdd(&cursor[d], 1);
    csr[offs[d] + p] = src[e];
}

// ---------------- weight transpose + bf16 convert ----------------
// Wt[n][k] (bf16) for n in [0,1024): 0-255 Wq, 256-511 Wk, 512-767 Wv, 768-1023 Wo

__global__ void __launch_bounds__(256) k_prep(
    const float* __restrict__ Wq, const float* __restrict__ Wk,
    const float* __restrict__ Wv, const float* __restrict__ Wo,
    u16* __restrict__ Wt) {
    __shared__ float tile[64][65];
    int t = threadIdx.x;
    int k0 = blockIdx.x * 64;   // 0..3
    int n0 = blockIdx.y * 64;   // 0..15
    int sel = n0 >> 8;          // uniform per block
    const float* W = (sel == 0) ? Wq : (sel == 1) ? Wk : (sel == 2) ? Wv : Wo;
    int ncol0 = n0 & 255;

#pragma unroll
    for (int p = 0; p < 16; p++) {
        int kk = p * 4 + (t >> 6);
        int nn = t & 63;
        tile[kk][nn] = W[(size_t)(k0 + kk) * DD + ncol0 + nn];
    }
    __syncthreads();
#pragma unroll
    for (int p = 0; p < 16; p++) {
        int nn = p * 4 + (t >> 6);
        int kk = t & 63;
        Wt[(size_t)(n0 + nn) * DD + k0 + kk] = f2b(tile[kk][nn]);
    }
}

// ---------------- LN1 -> xn bf16 (4 nodes per block) ----------------

__device__ __forceinline__ float4 blockReduce4(float4 v, float4* red) {
    int t = threadIdx.x;
    red[t] = v;
    __syncthreads();
#pragma unroll
    for (int s = 128; s > 0; s >>= 1) {
        if (t < s) {
            float4 a = red[t], b = red[t + s];
            red[t] = make_float4(a.x + b.x, a.y + b.y, a.z + b.z, a.w + b.w);
        }
        __syncthreads();
    }
    float4 r = red[0];
    __syncthreads();
    return r;
}

__global__ void __launch_bounds__(256) k_ln1(
    const float* __restrict__ x, const float* __restrict__ g1, const float* __restrict__ b1,
    int N_, u16* __restrict__ xn) {
    __shared__ float4 red[256];
    int t = threadIdx.x;
    int n0 = blockIdx.x * 4;
    float val[4];
#pragma unroll
    for (int r = 0; r < 4; r++) {
        int n = n0 + r;
        val[r] = (n < N_) ? x[(size_t)n * DD + t] : 0.f;
    }
    float4 s1 = blockReduce4(make_float4(val[0], val[1], val[2], val[3]), red);
    float mean[4] = {s1.x * (1.f / DD), s1.y * (1.f / DD), s1.z * (1.f / DD), s1.w * (1.f / DD)};
    float dv[4];
#pragma unroll
    for (int r = 0; r < 4; r++) dv[r] = val[r] - mean[r];
    float4 s2 = blockReduce4(make_float4(dv[0]*dv[0], dv[1]*dv[1], dv[2]*dv[2], dv[3]*dv[3]), red);
    float rstd[4] = {rsqrtf(s2.x * (1.f / DD) + LN_EPS), rsqrtf(s2.y * (1.f / DD) + LN_EPS),
                     rsqrtf(s2.z * (1.f / DD) + LN_EPS), rsqrtf(s2.w * (1.f / DD) + LN_EPS)};
    float gv = g1[t], bv1 = b1[t];
#pragma unroll
    for (int r = 0; r < 4; r++) {
        int n = n0 + r;
        if (n < N_) xn[(size_t)n * DD + t] = f2b(dv[r] * rstd[r] * gv + bv1);
    }
}

// ---------------- QKV GEMM via MFMA: [N_,256]bf16 x [256,768] -> q fp32, kv bf16 ----------------
// kv layout: kv[node*512 + h*128 + li*8 + j] = k[h*64+li*4+j]; +4 for v. (16B packet per lane)

__global__ void __launch_bounds__(256) k_qkv(
    const u16* __restrict__ xn, const u16* __restrict__ Wt,
    const float* __restrict__ bq, const float* __restrict__ bk, const float* __restrict__ bv,
    int N_, float* __restrict__ q, u16* __restrict__ kv) {
    __shared__ u16 As[128][72];
    __shared__ u16 Bs[128][72];
    int t = threadIdx.x;
    int m0 = blockIdx.x * 128;
    int nb0 = blockIdx.y * 128;
    int w = t >> 6, lane = t & 63;
    int wm = w >> 1, wn = w & 1;
    int li = lane & 15, quad = lane >> 4;

    floatx4 acc[4][4];
#pragma unroll
    for (int i = 0; i < 4; i++)
#pragma unroll
        for (int j = 0; j < 4; j++) acc[i][j] = (floatx4){0.f, 0.f, 0.f, 0.f};

    for (int kt = 0; kt < 4; kt++) {
        int k0 = kt * 64;
#pragma unroll
        for (int p = 0; p < 4; p++) {
            int flat = p * 2048 + t * 8;
            int row = flat >> 6, ck = flat & 63;
            int node = m0 + row;
            uint4 va;
            if (node < N_) va = *(const uint4*)&xn[(size_t)node * DD + k0 + ck];
            else va = make_uint4(0, 0, 0, 0);
            *(uint4*)&As[row][ck] = va;
            uint4 vb = *(const uint4*)&Wt[(size_t)(nb0 + row) * DD + k0 + ck];
            *(uint4*)&Bs[row][ck] = vb;
        }
        __syncthreads();
#pragma unroll
        for (int ks = 0; ks < 2; ks++) {
            int ko = ks * 32 + quad * 8;
            short8 a[4], b[4];
#pragma unroll
            for (int mi = 0; mi < 4; mi++) a[mi] = *(short8*)&As[wm * 64 + mi * 16 + li][ko];
#pragma unroll
            for (int ni = 0; ni < 4; ni++) b[ni] = *(short8*)&Bs[wn * 64 + ni * 16 + li][ko];
#pragma unroll
            for (int mi = 0; mi < 4; mi++)
#pragma unroll
                for (int ni = 0; ni < 4; ni++)
                    acc[mi][ni] = __builtin_amdgcn_mfma_f32_16x16x32_bf16(a[mi], b[ni], acc[mi][ni], 0, 0, 0);
        }
        __syncthreads();
    }

#pragma unroll
    for (int ni = 0; ni < 4; ni++) {
        int ncol = nb0 + wn * 64 + ni * 16 + li;
        int kind, c;
        float bias;
        if (ncol < 256)      { kind = 0; c = ncol;       bias = bq[c]; }
        else if (ncol < 512) { kind = 1; c = ncol - 256; bias = bk[c]; }
        else                 { kind = 2; c = ncol - 512; bias = bv[c]; }
#pragma unroll
        for (int mi = 0; mi < 4; mi++) {
#pragma unroll
            for (int r = 0; r < 4; r++) {
                int row = m0 + wm * 64 + mi * 16 + quad * 4 + r;
                if (row >= N_) continue;
                float val = acc[mi][ni][r] + bias;
                if (kind == 0) {
                    q[(size_t)row * DD + c] = val * 0.125f;  // fold 1/sqrt(64)
                } else {
                    size_t idx = (size_t)row * 512 + (c >> 6) * 128 + ((c & 63) >> 2) * 8 + (c & 3)
                               + (kind == 2 ? 4 : 0);
                    kv[idx] = f2b(val);
                }
            }
        }
    }
}

// ---------------- attention: block per node, wave per head, 4 edges x 16 lanes ----------------

__global__ void __launch_bounds__(256) k_attn(
    const float* __restrict__ q, const u16* __restrict__ kv,
    const int* __restrict__ offs, const int* __restrict__ csr,
    u16* __restrict__ agg) {
    int node = blockIdx.x;
    int t = threadIdx.x;
    int h = t >> 6;
    int lane = t & 63;
    int g = lane >> 4;
    int li = lane & 15;
    size_t obase = (size_t)node * DD + h * 64 + li * 4;

    int e0 = offs[node], e1 = offs[node + 1];
    if (e0 == e1) {
        if (g == 0) { uint2 z; z.x = 0u; z.y = 0u; *(uint2*)&agg[obase] = z; }
        return;
    }

    float4 qv = *(const float4*)&q[obase];
    float m = -INFINITY, l = 0.f;
    float ax = 0.f, ay = 0.f, az = 0.f, aw = 0.f;

    for (int e = e0; e < e1; e += 4) {
        int ee = e + g;
        bool valid = ee < e1;
        int src = csr[valid ? ee : e0];
        uint4 pk = *(const uint4*)&kv[(size_t)src * 512 + h * 128 + li * 8];
        float k0 = b2f(pk.x & 0xffff), k1 = b2f(pk.x >> 16);
        float k2 = b2f(pk.y & 0xffff), k3 = b2f(pk.y >> 16);
        float v0 = b2f(pk.z & 0xffff), v1 = b2f(pk.z >> 16);
        float v2 = b2f(pk.w & 0xffff), v3 = b2f(pk.w >> 16);
        float s = qv.x * k0 + qv.y * k1 + qv.z * k2 + qv.w * k3;
        s += __shfl_xor(s, 1); s += __shfl_xor(s, 2);
        s += __shfl_xor(s, 4); s += __shfl_xor(s, 8);
        if (!valid) s = -INFINITY;
        float smax = fmaxf(s, __shfl_xor(s, 16));
        smax = fmaxf(smax, __shfl_xor(smax, 32));
        float mn = fmaxf(m, smax);
        float p = __expf(s - mn);
        float sc = __expf(m - mn);
        float ps = p + __shfl_xor(p, 16);
        ps += __shfl_xor(ps, 32);
        l = l * sc + ps;
        ax = ax * sc + p * v0;
        ay = ay * sc + p * v1;
        az = az * sc + p * v2;
        aw = aw * sc + p * v3;
        m = mn;
    }
    ax += __shfl_xor(ax, 16); ax += __shfl_xor(ax, 32);
    ay += __shfl_xor(ay, 16); ay += __shfl_xor(ay, 32);
    az += __shfl_xor(az, 16); az += __shfl_xor(az, 32);
    aw += __shfl_xor(aw, 16); aw += __shfl_xor(aw, 32);
    if (g == 0) {
        float invl = 1.f / l;
        uint2 o;
        o.x = (unsigned)f2b(ax * invl) | ((unsigned)f2b(ay * invl) << 16);
        o.y = (unsigned)f2b(az * invl) | ((unsigned)f2b(aw * invl) << 16);
        *(uint2*)&agg[obase] = o;
    }
}

// ---------------- out GEMM (MFMA) + LN2 + relu + residual, 32 rows/block ----------------

__global__ void __launch_bounds__(128) k_out(
    const u16* __restrict__ agg, const u16* __restrict__ Wt,
    const float* __restrict__ bo, const float* __restrict__ g2, const float* __restrict__ b2,
    const float* __restrict__ x, int N_, float* __restrict__ out) {
    __shared__ u16 As[32][72];
    __shared__ u16 Bs[256][72];
    int t = threadIdx.x;
    int m0 = blockIdx.x * 32;
    int w = t >> 6, lane = t & 63;
    int li = lane & 15, quad = lane >> 4;

    floatx4 acc[16];
#pragma unroll
    for (int i = 0; i < 16; i++) acc[i] = (floatx4){0.f, 0.f, 0.f, 0.f};

    for (int kt = 0; kt < 4; kt++) {
        int k0 = kt * 64;
#pragma unroll
        for (int p = 0; p < 2; p++) {
            int flat = p * 1024 + t * 8;
            int row = flat >> 6, ck = flat & 63;
            int node = m0 + row;
            uint4 va;
            if (node < N_) va = *(const uint4*)&agg[(size_t)node * DD + k0 + ck];
            else va = make_uint4(0, 0, 0, 0);
            *(uint4*)&As[row][ck] = va;
        }
#pragma unroll
        for (int p = 0; p < 16; p++) {
            int flat = p * 1024 + t * 8;
            int row = flat >> 6, ck = flat & 63;
            uint4 vb = *(const uint4*)&Wt[(size_t)(768 + row) * DD + k0 + ck];
            *(uint4*)&Bs[row][ck] = vb;
        }
        __syncthreads();
#pragma unroll
        for (int ks = 0; ks < 2; ks++) {
            int ko = ks * 32 + quad * 8;
            short8 a = *(short8*)&As[w * 16 + li][ko];
#pragma unroll
            for (int nf = 0; nf < 16; nf++) {
                short8 b = *(short8*)&Bs[nf * 16 + li][ko];
                acc[nf] = __builtin_amdgcn_mfma_f32_16x16x32_bf16(a, b, acc[nf], 0, 0, 0);
            }
        }
        __syncthreads();
    }

#pragma unroll
    for (int nf = 0; nf < 16; nf++) {
        float bb = bo[nf * 16 + li];
#pragma unroll
        for (int r = 0; r < 4; r++) acc[nf][r] += bb;
    }

    float mean[4], rstd[4];
#pragma unroll
    for (int r = 0; r < 4; r++) {
        float s = 0.f;
#pragma unroll
        for (int nf = 0; nf < 16; nf++) s += acc[nf][r];
        s += __shfl_xor(s, 1); s += __shfl_xor(s, 2);
        s += __shfl_xor(s, 4); s += __shfl_xor(s, 8);
        mean[r] = s * (1.f / DD);
        float v = 0.f;
#pragma unroll
        for (int nf = 0; nf < 16; nf++) {
            float d = acc[nf][r] - mean[r];
            v += d * d;
        }
        v += __shfl_xor(v, 1); v += __shfl_xor(v, 2);
        v += __shfl_xor(v, 4); v += __shfl_xor(v, 8);
        rstd[r] = rsqrtf(v * (1.f / DD) + LN_EPS);
    }

#pragma unroll
    for (int nf = 0; nf < 16; nf++) {
        int col = nf * 16 + li;
        float gv = g2[col], bv2 = b2[col];
#pragma unroll
        for (int r = 0; r < 4; r++) {
            int row = m0 + w * 16 + quad * 4 + r;
            if (row >= N_) continue;
            float y = (acc[nf][r] - mean[r]) * rstd[r] * gv + bv2;
            y = fmaxf(y, 0.f);
            out[(size_t)row * DD + col] = x[(size_t)row * DD + col] + y;
        }
    }
}

// ---------------- launch ----------------

extern "C" void kernel_launch(void* const* d_in, const int* in_sizes, int n_in,
                              void* d_out, int out_size, void* d_ws, size_t ws_size,
                              hipStream_t stream) {
    const float* x  = (const float*)d_in[0];
    const int*   ei = (const int*)d_in[1];
    const float* g1 = (const float*)d_in[2];
    const float* b1 = (const float*)d_in[3];
    const float* g2 = (const float*)d_in[4];
    const float* b2 = (const float*)d_in[5];
    const float* Wq = (const float*)d_in[6];
    const float* bq = (const float*)d_in[7];
    const float* Wk = (const float*)d_in[8];
    const float* bk = (const float*)d_in[9];
    const float* Wv = (const float*)d_in[10];
    const float* bv = (const float*)d_in[11];
    const float* Wo = (const float*)d_in[12];
    const float* bo = (const float*)d_in[13];
    float* out = (float*)d_out;

    int N_ = in_sizes[0] / DD;
    int E_ = in_sizes[1] / 2;
    const int* srcp = ei;
    const int* dstp = ei + E_;

    char* w = (char*)d_ws;
    float* q   = (float*)w;  w += (size_t)N_ * DD * 4;
    u16* xn    = (u16*)w;    w += (size_t)N_ * DD * 2;
    u16* kv    = (u16*)w;    w += (size_t)N_ * 512 * 2;
    u16* agg   = (u16*)w;    w += (size_t)N_ * DD * 2;
    u16* Wt    = (u16*)w;    w += (size_t)1024 * DD * 2;
    int* deg    = (int*)w;   w += (size_t)N_ * 4;
    int* offs   = (int*)w;   w += (size_t)(N_ + 1) * 4;
    int* cursor = (int*)w;   w += (size_t)N_ * 4;
    int* csr    = (int*)w;   w += (size_t)E_ * 4;

    k_zero<<<(N_ + 255) / 256, 256, 0, stream>>>(deg, N_);
    k_count<<<(E_ + 255) / 256, 256, 0, stream>>>(dstp, E_, deg);
    k_scan<<<1, 1024, 0, stream>>>(deg, N_, offs, cursor);
    k_fill<<<(E_ + 255) / 256, 256, 0, stream>>>(srcp, dstp, E_, offs, cursor, csr);
    k_prep<<<dim3(4, 16), 256, 0, stream>>>(Wq, Wk, Wv, Wo, Wt);
    k_ln1<<<(N_ + 3) / 4, 256, 0, stream>>>(x, g1, b1, N_, xn);
    k_qkv<<<dim3((N_ + 127) / 128, 6), 256, 0, stream>>>(xn, Wt, bq, bk, bv, N_, q, kv);
    k_attn<<<N_, 256, 0, stream>>>(q, kv, offs, csr, agg);
    k_out<<<(N_ + 31) / 32, 128, 0, stream>>>(agg, Wt, bo, g2, b2, x, N_, out);
}

// Round 5
// 247.664 us; speedup vs baseline: 1.4972x; 1.0715x over previous
//
#include <hip/hip_runtime.h>
#include <hip/hip_bf16.h>
#include <math.h>

#define DD 256
#define LN_EPS 1e-5f

typedef unsigned short u16;
typedef __attribute__((ext_vector_type(8))) short short8;
typedef __attribute__((ext_vector_type(4))) float floatx4;

__device__ __forceinline__ u16 f2b(float f) {
    __hip_bfloat16 h = __float2bfloat16(f);
    return *reinterpret_cast<u16*>(&h);
}
__device__ __forceinline__ float b2f(unsigned int u) {
    union { unsigned int i; float f; } x;
    x.i = u << 16;
    return x.f;
}

// ---------------- CSR build ----------------

__global__ void k_zero(int* __restrict__ p, int n) {
    int i = blockIdx.x * 256 + threadIdx.x;
    if (i < n) p[i] = 0;
}

__global__ void k_count(const int* __restrict__ dst, int E_, int* __restrict__ deg) {
    int e = blockIdx.x * 256 + threadIdx.x;
    if (e < E_) atomicAdd(&deg[dst[e]], 1);
}

__global__ void __launch_bounds__(1024) k_scan(const int* __restrict__ deg, int N_,
                                               int* __restrict__ offs, int* __restrict__ cursor) {
    __shared__ int part[1024];
    int t = threadIdx.x;
    int items = (N_ + 1023) >> 10;
    if (items > 16) items = 16;
    int base = t * items;
    int loc[16];
    int s = 0;
    for (int i = 0; i < items; i++) {
        int idx = base + i;
        int d = (idx < N_) ? deg[idx] : 0;
        loc[i] = s;
        s += d;
    }
    part[t] = s;
    __syncthreads();
    for (int off = 1; off < 1024; off <<= 1) {
        int v = (t >= off) ? part[t - off] : 0;
        __syncthreads();
        part[t] += v;
        __syncthreads();
    }
    int excl = (t > 0) ? part[t - 1] : 0;
    for (int i = 0; i < items; i++) {
        int idx = base + i;
        if (idx < N_) {
            offs[idx] = excl + loc[i];
            cursor[idx] = 0;
        }
    }
    if (t == 0) offs[N_] = part[1023];
}

__global__ void k_fill(const int* __restrict__ src, const int* __restrict__ dst, int E_,
                       const int* __restrict__ offs, int* __restrict__ cursor,
                       int* __restrict__ csr) {
    int e = blockIdx.x * 256 + threadIdx.x;
    if (e >= E_) return;
    int d = dst[e];
    int p = atomicAdd(&cursor[d], 1);
    csr[offs[d] + p] = src[e];
}

// ---------------- weight transpose + bf16 convert ----------------
// Wt[n][k] (bf16) for n in [0,1024): 0-255 Wq, 256-511 Wk, 512-767 Wv, 768-1023 Wo

__global__ void __launch_bounds__(256) k_prep(
    const float* __restrict__ Wq, const float* __restrict__ Wk,
    const float* __restrict__ Wv, const float* __restrict__ Wo,
    u16* __restrict__ Wt) {
    __shared__ float tile[64][65];
    int t = threadIdx.x;
    int k0 = blockIdx.x * 64;   // 0..3
    int n0 = blockIdx.y * 64;   // 0..15
    int sel = n0 >> 8;          // uniform per block
    const float* W = (sel == 0) ? Wq : (sel == 1) ? Wk : (sel == 2) ? Wv : Wo;
    int ncol0 = n0 & 255;

#pragma unroll
    for (int p = 0; p < 16; p++) {
        int kk = p * 4 + (t >> 6);
        int nn = t & 63;
        tile[kk][nn] = W[(size_t)(k0 + kk) * DD + ncol0 + nn];
    }
    __syncthreads();
#pragma unroll
    for (int p = 0; p < 16; p++) {
        int nn = p * 4 + (t >> 6);
        int kk = t & 63;
        Wt[(size_t)(n0 + nn) * DD + k0 + kk] = f2b(tile[kk][nn]);
    }
}

// ---------------- LN1 -> xn bf16 (wave per node, shuffle-only) ----------------

__global__ void __launch_bounds__(256) k_ln1(
    const float* __restrict__ x, const float* __restrict__ g1, const float* __restrict__ b1,
    int N_, u16* __restrict__ xn) {
    int t = threadIdx.x;
    int lane = t & 63;
    int node = blockIdx.x * 4 + (t >> 6);
    if (node >= N_) return;
    size_t base = (size_t)node * DD + lane * 4;
    float4 xv = *(const float4*)&x[base];
    float s = xv.x + xv.y + xv.z + xv.w;
    s += __shfl_xor(s, 1); s += __shfl_xor(s, 2); s += __shfl_xor(s, 4);
    s += __shfl_xor(s, 8); s += __shfl_xor(s, 16); s += __shfl_xor(s, 32);
    float mean = s * (1.f / DD);
    float d0 = xv.x - mean, d1 = xv.y - mean, d2 = xv.z - mean, d3 = xv.w - mean;
    float v = d0 * d0 + d1 * d1 + d2 * d2 + d3 * d3;
    v += __shfl_xor(v, 1); v += __shfl_xor(v, 2); v += __shfl_xor(v, 4);
    v += __shfl_xor(v, 8); v += __shfl_xor(v, 16); v += __shfl_xor(v, 32);
    float rstd = rsqrtf(v * (1.f / DD) + LN_EPS);
    float4 gv = *(const float4*)&g1[lane * 4];
    float4 bv = *(const float4*)&b1[lane * 4];
    uint2 o;
    o.x = (unsigned)f2b(d0 * rstd * gv.x + bv.x) | ((unsigned)f2b(d1 * rstd * gv.y + bv.y) << 16);
    o.y = (unsigned)f2b(d2 * rstd * gv.z + bv.z) | ((unsigned)f2b(d3 * rstd * gv.w + bv.w) << 16);
    *(uint2*)&xn[base] = o;
}

// ---------------- QKV GEMM via MFMA: [N_,256]bf16 x [256,768] -> q fp32, kv bf16 ----------------
// kv layout: kv[node*512 + h*128 + li*8 + j] = k[h*64+li*4+j]; +4 for v. (16B packet per lane)

__global__ void __launch_bounds__(256) k_qkv(
    const u16* __restrict__ xn, const u16* __restrict__ Wt,
    const float* __restrict__ bq, const float* __restrict__ bk, const float* __restrict__ bv,
    int N_, float* __restrict__ q, u16* __restrict__ kv) {
    __shared__ u16 As[128][72];
    __shared__ u16 Bs[128][72];
    int t = threadIdx.x;
    int m0 = blockIdx.x * 128;
    int nb0 = blockIdx.y * 128;
    int w = t >> 6, lane = t & 63;
    int wm = w >> 1, wn = w & 1;
    int li = lane & 15, quad = lane >> 4;

    floatx4 acc[4][4];
#pragma unroll
    for (int i = 0; i < 4; i++)
#pragma unroll
        for (int j = 0; j < 4; j++) acc[i][j] = (floatx4){0.f, 0.f, 0.f, 0.f};

    for (int kt = 0; kt < 4; kt++) {
        int k0 = kt * 64;
#pragma unroll
        for (int p = 0; p < 4; p++) {
            int flat = p * 2048 + t * 8;
            int row = flat >> 6, ck = flat & 63;
            int node = m0 + row;
            uint4 va;
            if (node < N_) va = *(const uint4*)&xn[(size_t)node * DD + k0 + ck];
            else va = make_uint4(0, 0, 0, 0);
            *(uint4*)&As[row][ck] = va;
            uint4 vb = *(const uint4*)&Wt[(size_t)(nb0 + row) * DD + k0 + ck];
            *(uint4*)&Bs[row][ck] = vb;
        }
        __syncthreads();
#pragma unroll
        for (int ks = 0; ks < 2; ks++) {
            int ko = ks * 32 + quad * 8;
            short8 a[4], b[4];
#pragma unroll
            for (int mi = 0; mi < 4; mi++) a[mi] = *(short8*)&As[wm * 64 + mi * 16 + li][ko];
#pragma unroll
            for (int ni = 0; ni < 4; ni++) b[ni] = *(short8*)&Bs[wn * 64 + ni * 16 + li][ko];
#pragma unroll
            for (int mi = 0; mi < 4; mi++)
#pragma unroll
                for (int ni = 0; ni < 4; ni++)
                    acc[mi][ni] = __builtin_amdgcn_mfma_f32_16x16x32_bf16(a[mi], b[ni], acc[mi][ni], 0, 0, 0);
        }
        __syncthreads();
    }

#pragma unroll
    for (int ni = 0; ni < 4; ni++) {
        int ncol = nb0 + wn * 64 + ni * 16 + li;
        int kind, c;
        float bias;
        if (ncol < 256)      { kind = 0; c = ncol;       bias = bq[c]; }
        else if (ncol < 512) { kind = 1; c = ncol - 256; bias = bk[c]; }
        else                 { kind = 2; c = ncol - 512; bias = bv[c]; }
#pragma unroll
        for (int mi = 0; mi < 4; mi++) {
#pragma unroll
            for (int r = 0; r < 4; r++) {
                int row = m0 + wm * 64 + mi * 16 + quad * 4 + r;
                if (row >= N_) continue;
                float val = acc[mi][ni][r] + bias;
                if (kind == 0) {
                    q[(size_t)row * DD + c] = val * 0.125f;  // fold 1/sqrt(64)
                } else {
                    size_t idx = (size_t)row * 512 + (c >> 6) * 128 + ((c & 63) >> 2) * 8 + (c & 3)
                               + (kind == 2 ? 4 : 0);
                    kv[idx] = f2b(val);
                }
            }
        }
    }
}

// ---------------- attention: block per node, wave per head, no-max softmax ----------------
// Softmax is shift-invariant and scores are O(1) (q,k unit-variance, /8 folded),
// so we drop the running-max: plain exp accumulation, no cross-iteration dependency.

__global__ void __launch_bounds__(256) k_attn(
    const float* __restrict__ q, const u16* __restrict__ kv,
    const int* __restrict__ offs, const int* __restrict__ csr,
    u16* __restrict__ agg) {
    int node = blockIdx.x;
    int t = threadIdx.x;
    int h = t >> 6;
    int lane = t & 63;
    int g = lane >> 4;
    int li = lane & 15;
    size_t obase = (size_t)node * DD + h * 64 + li * 4;

    int e0 = offs[node], e1 = offs[node + 1];
    if (e0 == e1) {
        if (g == 0) { uint2 z; z.x = 0u; z.y = 0u; *(uint2*)&agg[obase] = z; }
        return;
    }

    float4 qv = *(const float4*)&q[obase];
    int last = e1 - 1;
    size_t kvoff = (size_t)h * 128 + li * 8;

    float l = 0.f;
    float ax = 0.f, ay = 0.f, az = 0.f, aw = 0.f;

    int ia = e0 + g, ib = e0 + 4 + g;
    int src_a = csr[ia <= last ? ia : last];
    int src_b = csr[ib <= last ? ib : last];

    for (int e = e0; e < e1; e += 8) {
        // issue both kv gathers (srcs already in registers)
        uint4 pa = *(const uint4*)&kv[(size_t)src_a * 512 + kvoff];
        uint4 pb = *(const uint4*)&kv[(size_t)src_b * 512 + kvoff];
        // prefetch next pair's indices while gathers are in flight
        int na = e + 8 + g, nb = e + 12 + g;
        src_a = csr[na <= last ? na : last];
        src_b = csr[nb <= last ? nb : last];
        bool va = (e + g) < e1;
        bool vb = (e + 4 + g) < e1;

        float ka0 = b2f(pa.x & 0xffff), ka1 = b2f(pa.x >> 16);
        float ka2 = b2f(pa.y & 0xffff), ka3 = b2f(pa.y >> 16);
        float sa = qv.x * ka0 + qv.y * ka1 + qv.z * ka2 + qv.w * ka3;
        sa += __shfl_xor(sa, 1); sa += __shfl_xor(sa, 2);
        sa += __shfl_xor(sa, 4); sa += __shfl_xor(sa, 8);
        float p_a = va ? __expf(sa) : 0.f;

        float kb0 = b2f(pb.x & 0xffff), kb1 = b2f(pb.x >> 16);
        float kb2 = b2f(pb.y & 0xffff), kb3 = b2f(pb.y >> 16);
        float sb = qv.x * kb0 + qv.y * kb1 + qv.z * kb2 + qv.w * kb3;
        sb += __shfl_xor(sb, 1); sb += __shfl_xor(sb, 2);
        sb += __shfl_xor(sb, 4); sb += __shfl_xor(sb, 8);
        float p_b = vb ? __expf(sb) : 0.f;

        l += p_a + p_b;
        ax += p_a * b2f(pa.z & 0xffff) + p_b * b2f(pb.z & 0xffff);
        ay += p_a * b2f(pa.z >> 16)    + p_b * b2f(pb.z >> 16);
        az += p_a * b2f(pa.w & 0xffff) + p_b * b2f(pb.w & 0xffff);
        aw += p_a * b2f(pa.w >> 16)    + p_b * b2f(pb.w >> 16);
    }

    // cross-group reduction (deferred to end — no per-iteration rescale)
    l  += __shfl_xor(l, 16);  l  += __shfl_xor(l, 32);
    ax += __shfl_xor(ax, 16); ax += __shfl_xor(ax, 32);
    ay += __shfl_xor(ay, 16); ay += __shfl_xor(ay, 32);
    az += __shfl_xor(az, 16); az += __shfl_xor(az, 32);
    aw += __shfl_xor(aw, 16); aw += __shfl_xor(aw, 32);
    if (g == 0) {
        float invl = 1.f / l;
        uint2 o;
        o.x = (unsigned)f2b(ax * invl) | ((unsigned)f2b(ay * invl) << 16);
        o.y = (unsigned)f2b(az * invl) | ((unsigned)f2b(aw * invl) << 16);
        *(uint2*)&agg[obase] = o;
    }
}

// ---------------- out GEMM (MFMA) + LN2 + relu + residual, 32 rows/block ----------------

__global__ void __launch_bounds__(128) k_out(
    const u16* __restrict__ agg, const u16* __restrict__ Wt,
    const float* __restrict__ bo, const float* __restrict__ g2, const float* __restrict__ b2,
    const float* __restrict__ x, int N_, float* __restrict__ out) {
    __shared__ u16 As[32][72];
    __shared__ u16 Bs[256][72];
    int t = threadIdx.x;
    int m0 = blockIdx.x * 32;
    int w = t >> 6, lane = t & 63;
    int li = lane & 15, quad = lane >> 4;

    floatx4 acc[16];
#pragma unroll
    for (int i = 0; i < 16; i++) acc[i] = (floatx4){0.f, 0.f, 0.f, 0.f};

    for (int kt = 0; kt < 4; kt++) {
        int k0 = kt * 64;
#pragma unroll
        for (int p = 0; p < 2; p++) {
            int flat = p * 1024 + t * 8;
            int row = flat >> 6, ck = flat & 63;
            int node = m0 + row;
            uint4 va;
            if (node < N_) va = *(const uint4*)&agg[(size_t)node * DD + k0 + ck];
            else va = make_uint4(0, 0, 0, 0);
            *(uint4*)&As[row][ck] = va;
        }
#pragma unroll
        for (int p = 0; p < 16; p++) {
            int flat = p * 1024 + t * 8;
            int row = flat >> 6, ck = flat & 63;
            uint4 vb = *(const uint4*)&Wt[(size_t)(768 + row) * DD + k0 + ck];
            *(uint4*)&Bs[row][ck] = vb;
        }
        __syncthreads();
#pragma unroll
        for (int ks = 0; ks < 2; ks++) {
            int ko = ks * 32 + quad * 8;
            short8 a = *(short8*)&As[w * 16 + li][ko];
#pragma unroll
            for (int nf = 0; nf < 16; nf++) {
                short8 b = *(short8*)&Bs[nf * 16 + li][ko];
                acc[nf] = __builtin_amdgcn_mfma_f32_16x16x32_bf16(a, b, acc[nf], 0, 0, 0);
            }
        }
        __syncthreads();
    }

#pragma unroll
    for (int nf = 0; nf < 16; nf++) {
        float bb = bo[nf * 16 + li];
#pragma unroll
        for (int r = 0; r < 4; r++) acc[nf][r] += bb;
    }

    float mean[4], rstd[4];
#pragma unroll
    for (int r = 0; r < 4; r++) {
        float s = 0.f;
#pragma unroll
        for (int nf = 0; nf < 16; nf++) s += acc[nf][r];
        s += __shfl_xor(s, 1); s += __shfl_xor(s, 2);
        s += __shfl_xor(s, 4); s += __shfl_xor(s, 8);
        mean[r] = s * (1.f / DD);
        float v = 0.f;
#pragma unroll
        for (int nf = 0; nf < 16; nf++) {
            float d = acc[nf][r] - mean[r];
            v += d * d;
        }
        v += __shfl_xor(v, 1); v += __shfl_xor(v, 2);
        v += __shfl_xor(v, 4); v += __shfl_xor(v, 8);
        rstd[r] = rsqrtf(v * (1.f / DD) + LN_EPS);
    }

#pragma unroll
    for (int nf = 0; nf < 16; nf++) {
        int col = nf * 16 + li;
        float gv = g2[col], bv2 = b2[col];
#pragma unroll
        for (int r = 0; r < 4; r++) {
            int row = m0 + w * 16 + quad * 4 + r;
            if (row >= N_) continue;
            float y = (acc[nf][r] - mean[r]) * rstd[r] * gv + bv2;
            y = fmaxf(y, 0.f);
            out[(size_t)row * DD + col] = x[(size_t)row * DD + col] + y;
        }
    }
}

// ---------------- launch ----------------

extern "C" void kernel_launch(void* const* d_in, const int* in_sizes, int n_in,
                              void* d_out, int out_size, void* d_ws, size_t ws_size,
                              hipStream_t stream) {
    const float* x  = (const float*)d_in[0];
    const int*   ei = (const int*)d_in[1];
    const float* g1 = (const float*)d_in[2];
    const float* b1 = (const float*)d_in[3];
    const float* g2 = (const float*)d_in[4];
    const float* b2 = (const float*)d_in[5];
    const float* Wq = (const float*)d_in[6];
    const float* bq = (const float*)d_in[7];
    const float* Wk = (const float*)d_in[8];
    const float* bk = (const float*)d_in[9];
    const float* Wv = (const float*)d_in[10];
    const float* bv = (const float*)d_in[11];
    const float* Wo = (const float*)d_in[12];
    const float* bo = (const float*)d_in[13];
    float* out = (float*)d_out;

    int N_ = in_sizes[0] / DD;
    int E_ = in_sizes[1] / 2;
    const int* srcp = ei;
    const int* dstp = ei + E_;

    char* w = (char*)d_ws;
    float* q   = (float*)w;  w += (size_t)N_ * DD * 4;
    u16* xn    = (u16*)w;    w += (size_t)N_ * DD * 2;
    u16* kv    = (u16*)w;    w += (size_t)N_ * 512 * 2;
    u16* agg   = (u16*)w;    w += (size_t)N_ * DD * 2;
    u16* Wt    = (u16*)w;    w += (size_t)1024 * DD * 2;
    int* deg    = (int*)w;   w += (size_t)N_ * 4;
    int* offs   = (int*)w;   w += (size_t)(N_ + 1) * 4;
    int* cursor = (int*)w;   w += (size_t)N_ * 4;
    int* csr    = (int*)w;   w += (size_t)E_ * 4;

    k_zero<<<(N_ + 255) / 256, 256, 0, stream>>>(deg, N_);
    k_count<<<(E_ + 255) / 256, 256, 0, stream>>>(dstp, E_, deg);
    k_scan<<<1, 1024, 0, stream>>>(deg, N_, offs, cursor);
    k_fill<<<(E_ + 255) / 256, 256, 0, stream>>>(srcp, dstp, E_, offs, cursor, csr);
    k_prep<<<dim3(4, 16), 256, 0, stream>>>(Wq, Wk, Wv, Wo, Wt);
    k_ln1<<<(N_ + 3) / 4, 256, 0, stream>>>(x, g1, b1, N_, xn);
    k_qkv<<<dim3((N_ + 127) / 128, 6), 256, 0, stream>>>(xn, Wt, bq, bk, bv, N_, q, kv);
    k_attn<<<N_, 256, 0, stream>>>(q, kv, offs, csr, agg);
    k_out<<<(N_ + 31) / 32, 128, 0, stream>>>(agg, Wt, bo, g2, b2, x, N_, out);
}

// Round 6
// 227.210 us; speedup vs baseline: 1.6320x; 1.0900x over previous
//
#include <hip/hip_runtime.h>
#include <hip/hip_bf16.h>
#include <math.h>

#define DD 256
#define LN_EPS 1e-5f

typedef unsigned short u16;
typedef __attribute__((ext_vector_type(8))) short short8;
typedef __attribute__((ext_vector_type(4))) float floatx4;

__device__ __forceinline__ u16 f2b(float f) {
    __hip_bfloat16 h = __float2bfloat16(f);
    return *reinterpret_cast<u16*>(&h);
}
__device__ __forceinline__ float b2f(unsigned int u) {
    union { unsigned int i; float f; } x;
    x.i = u << 16;
    return x.f;
}

// ---------------- CSR build ----------------

__global__ void k_zero(int* __restrict__ p, int n) {
    int i = blockIdx.x * 256 + threadIdx.x;
    if (i < n) p[i] = 0;
}

__global__ void k_count(const int* __restrict__ dst, int E_, int* __restrict__ deg) {
    int e = blockIdx.x * 256 + threadIdx.x;
    if (e < E_) atomicAdd(&deg[dst[e]], 1);
}

__global__ void __launch_bounds__(1024) k_scan(const int* __restrict__ deg, int N_,
                                               int* __restrict__ offs, int* __restrict__ cursor) {
    __shared__ int part[1024];
    int t = threadIdx.x;
    int items = (N_ + 1023) >> 10;
    if (items > 16) items = 16;
    int base = t * items;
    int loc[16];
    int s = 0;
    for (int i = 0; i < items; i++) {
        int idx = base + i;
        int d = (idx < N_) ? deg[idx] : 0;
        loc[i] = s;
        s += d;
    }
    part[t] = s;
    __syncthreads();
    for (int off = 1; off < 1024; off <<= 1) {
        int v = (t >= off) ? part[t - off] : 0;
        __syncthreads();
        part[t] += v;
        __syncthreads();
    }
    int excl = (t > 0) ? part[t - 1] : 0;
    for (int i = 0; i < items; i++) {
        int idx = base + i;
        if (idx < N_) {
            offs[idx] = excl + loc[i];
            cursor[idx] = 0;
        }
    }
    if (t == 0) offs[N_] = part[1023];
}

__global__ void k_fill(const int* __restrict__ src, const int* __restrict__ dst, int E_,
                       const int* __restrict__ offs, int* __restrict__ cursor,
                       int* __restrict__ csr) {
    int e = blockIdx.x * 256 + threadIdx.x;
    if (e >= E_) return;
    int d = dst[e];
    int p = atomicAdd(&cursor[d], 1);
    csr[offs[d] + p] = src[e];
}

// ---------------- weight transpose + bf16 convert ----------------
// Wt[n][k] (bf16) for n in [0,1024): 0-255 Wq, 256-511 Wk, 512-767 Wv, 768-1023 Wo

__global__ void __launch_bounds__(256) k_prep(
    const float* __restrict__ Wq, const float* __restrict__ Wk,
    const float* __restrict__ Wv, const float* __restrict__ Wo,
    u16* __restrict__ Wt) {
    __shared__ float tile[64][65];
    int t = threadIdx.x;
    int k0 = blockIdx.x * 64;   // 0..3
    int n0 = blockIdx.y * 64;   // 0..15
    int sel = n0 >> 8;          // uniform per block
    const float* W = (sel == 0) ? Wq : (sel == 1) ? Wk : (sel == 2) ? Wv : Wo;
    int ncol0 = n0 & 255;

#pragma unroll
    for (int p = 0; p < 16; p++) {
        int kk = p * 4 + (t >> 6);
        int nn = t & 63;
        tile[kk][nn] = W[(size_t)(k0 + kk) * DD + ncol0 + nn];
    }
    __syncthreads();
#pragma unroll
    for (int p = 0; p < 16; p++) {
        int nn = p * 4 + (t >> 6);
        int kk = t & 63;
        Wt[(size_t)(n0 + nn) * DD + k0 + kk] = f2b(tile[kk][nn]);
    }
}

// ---------------- LN1 -> xn bf16 (wave per node, shuffle-only) ----------------

__global__ void __launch_bounds__(256) k_ln1(
    const float* __restrict__ x, const float* __restrict__ g1, const float* __restrict__ b1,
    int N_, u16* __restrict__ xn) {
    int t = threadIdx.x;
    int lane = t & 63;
    int node = blockIdx.x * 4 + (t >> 6);
    if (node >= N_) return;
    size_t base = (size_t)node * DD + lane * 4;
    float4 xv = *(const float4*)&x[base];
    float s = xv.x + xv.y + xv.z + xv.w;
    s += __shfl_xor(s, 1); s += __shfl_xor(s, 2); s += __shfl_xor(s, 4);
    s += __shfl_xor(s, 8); s += __shfl_xor(s, 16); s += __shfl_xor(s, 32);
    float mean = s * (1.f / DD);
    float d0 = xv.x - mean, d1 = xv.y - mean, d2 = xv.z - mean, d3 = xv.w - mean;
    float v = d0 * d0 + d1 * d1 + d2 * d2 + d3 * d3;
    v += __shfl_xor(v, 1); v += __shfl_xor(v, 2); v += __shfl_xor(v, 4);
    v += __shfl_xor(v, 8); v += __shfl_xor(v, 16); v += __shfl_xor(v, 32);
    float rstd = rsqrtf(v * (1.f / DD) + LN_EPS);
    float4 gv = *(const float4*)&g1[lane * 4];
    float4 bv = *(const float4*)&b1[lane * 4];
    uint2 o;
    o.x = (unsigned)f2b(d0 * rstd * gv.x + bv.x) | ((unsigned)f2b(d1 * rstd * gv.y + bv.y) << 16);
    o.y = (unsigned)f2b(d2 * rstd * gv.z + bv.z) | ((unsigned)f2b(d3 * rstd * gv.w + bv.w) << 16);
    *(uint2*)&xn[base] = o;
}

// ---------------- QKV GEMM via MFMA: [N_,256]bf16 x [256,768] -> q fp32, kv bf16 ----------------
// kv layout: kv[node*512 + h*128 + li*8 + j] = k[h*64+li*4+j]; +4 for v. (16B packet per lane)

__global__ void __launch_bounds__(256) k_qkv(
    const u16* __restrict__ xn, const u16* __restrict__ Wt,
    const float* __restrict__ bq, const float* __restrict__ bk, const float* __restrict__ bv,
    int N_, float* __restrict__ q, u16* __restrict__ kv) {
    __shared__ u16 As[128][72];
    __shared__ u16 Bs[128][72];
    int t = threadIdx.x;
    int m0 = blockIdx.x * 128;
    int nb0 = blockIdx.y * 128;
    int w = t >> 6, lane = t & 63;
    int wm = w >> 1, wn = w & 1;
    int li = lane & 15, quad = lane >> 4;

    floatx4 acc[4][4];
#pragma unroll
    for (int i = 0; i < 4; i++)
#pragma unroll
        for (int j = 0; j < 4; j++) acc[i][j] = (floatx4){0.f, 0.f, 0.f, 0.f};

    for (int kt = 0; kt < 4; kt++) {
        int k0 = kt * 64;
#pragma unroll
        for (int p = 0; p < 4; p++) {
            int flat = p * 2048 + t * 8;
            int row = flat >> 6, ck = flat & 63;
            int node = m0 + row;
            uint4 va;
            if (node < N_) va = *(const uint4*)&xn[(size_t)node * DD + k0 + ck];
            else va = make_uint4(0, 0, 0, 0);
            *(uint4*)&As[row][ck] = va;
            uint4 vb = *(const uint4*)&Wt[(size_t)(nb0 + row) * DD + k0 + ck];
            *(uint4*)&Bs[row][ck] = vb;
        }
        __syncthreads();
#pragma unroll
        for (int ks = 0; ks < 2; ks++) {
            int ko = ks * 32 + quad * 8;
            short8 a[4], b[4];
#pragma unroll
            for (int mi = 0; mi < 4; mi++) a[mi] = *(short8*)&As[wm * 64 + mi * 16 + li][ko];
#pragma unroll
            for (int ni = 0; ni < 4; ni++) b[ni] = *(short8*)&Bs[wn * 64 + ni * 16 + li][ko];
#pragma unroll
            for (int mi = 0; mi < 4; mi++)
#pragma unroll
                for (int ni = 0; ni < 4; ni++)
                    acc[mi][ni] = __builtin_amdgcn_mfma_f32_16x16x32_bf16(a[mi], b[ni], acc[mi][ni], 0, 0, 0);
        }
        __syncthreads();
    }

#pragma unroll
    for (int ni = 0; ni < 4; ni++) {
        int ncol = nb0 + wn * 64 + ni * 16 + li;
        int kind, c;
        float bias;
        if (ncol < 256)      { kind = 0; c = ncol;       bias = bq[c]; }
        else if (ncol < 512) { kind = 1; c = ncol - 256; bias = bk[c]; }
        else                 { kind = 2; c = ncol - 512; bias = bv[c]; }
#pragma unroll
        for (int mi = 0; mi < 4; mi++) {
#pragma unroll
            for (int r = 0; r < 4; r++) {
                int row = m0 + wm * 64 + mi * 16 + quad * 4 + r;
                if (row >= N_) continue;
                float val = acc[mi][ni][r] + bias;
                if (kind == 0) {
                    q[(size_t)row * DD + c] = val * 0.125f;  // fold 1/sqrt(64)
                } else {
                    size_t idx = (size_t)row * 512 + (c >> 6) * 128 + ((c & 63) >> 2) * 8 + (c & 3)
                               + (kind == 2 ? 4 : 0);
                    kv[idx] = f2b(val);
                }
            }
        }
    }
}

// ---------------- attention: block per node, wave per head, no-max softmax, 4-deep ILP ----------------

__global__ void __launch_bounds__(256) k_attn(
    const float* __restrict__ q, const u16* __restrict__ kv,
    const int* __restrict__ offs, const int* __restrict__ csr,
    u16* __restrict__ agg) {
    int node = blockIdx.x;
    int t = threadIdx.x;
    int h = t >> 6;
    int lane = t & 63;
    int g = lane >> 4;
    int li = lane & 15;
    size_t obase = (size_t)node * DD + h * 64 + li * 4;

    int e0 = offs[node], e1 = offs[node + 1];
    if (e0 == e1) {
        if (g == 0) { uint2 z; z.x = 0u; z.y = 0u; *(uint2*)&agg[obase] = z; }
        return;
    }

    float4 qv = *(const float4*)&q[obase];
    int last = e1 - 1;
    size_t kvoff = (size_t)h * 128 + li * 8;

    float l = 0.f;
    float ax = 0.f, ay = 0.f, az = 0.f, aw = 0.f;

    int src[4];
#pragma unroll
    for (int d = 0; d < 4; d++) {
        int i = e0 + d * 4 + g;
        src[d] = csr[i <= last ? i : last];
    }

    for (int e = e0; e < e1; e += 16) {
        uint4 p[4];
#pragma unroll
        for (int d = 0; d < 4; d++) p[d] = *(const uint4*)&kv[(size_t)src[d] * 512 + kvoff];
        // prefetch next iteration's indices while gathers are in flight
#pragma unroll
        for (int d = 0; d < 4; d++) {
            int i = e + 16 + d * 4 + g;
            src[d] = csr[i <= last ? i : last];
        }
#pragma unroll
        for (int d = 0; d < 4; d++) {
            bool valid = (e + d * 4 + g) < e1;
            float s = qv.x * b2f(p[d].x & 0xffff) + qv.y * b2f(p[d].x >> 16)
                    + qv.z * b2f(p[d].y & 0xffff) + qv.w * b2f(p[d].y >> 16);
            s += __shfl_xor(s, 1); s += __shfl_xor(s, 2);
            s += __shfl_xor(s, 4); s += __shfl_xor(s, 8);
            float pe = valid ? __expf(s) : 0.f;
            l += pe;
            ax += pe * b2f(p[d].z & 0xffff);
            ay += pe * b2f(p[d].z >> 16);
            az += pe * b2f(p[d].w & 0xffff);
            aw += pe * b2f(p[d].w >> 16);
        }
    }

    l  += __shfl_xor(l, 16);  l  += __shfl_xor(l, 32);
    ax += __shfl_xor(ax, 16); ax += __shfl_xor(ax, 32);
    ay += __shfl_xor(ay, 16); ay += __shfl_xor(ay, 32);
    az += __shfl_xor(az, 16); az += __shfl_xor(az, 32);
    aw += __shfl_xor(aw, 16); aw += __shfl_xor(aw, 32);
    if (g == 0) {
        float invl = 1.f / l;
        uint2 o;
        o.x = (unsigned)f2b(ax * invl) | ((unsigned)f2b(ay * invl) << 16);
        o.y = (unsigned)f2b(az * invl) | ((unsigned)f2b(aw * invl) << 16);
        *(uint2*)&agg[obase] = o;
    }
}

// ---------------- out GEMM: no-LDS direct-from-L2 MFMA + LN2 + relu + residual ----------------
// 32 rows/block, 256 threads = 4 waves, wave w owns cols [w*64, w*64+64).
// A (agg) and B (Wt, n-major k-contiguous) fragments loaded straight from global:
// both are bf16 with K contiguous, exactly the MFMA operand layout. No K-loop barriers.

__global__ void __launch_bounds__(256) k_out(
    const u16* __restrict__ agg, const u16* __restrict__ Wt,
    const float* __restrict__ bo, const float* __restrict__ g2, const float* __restrict__ b2,
    const float* __restrict__ x, int N_, float* __restrict__ out) {
    __shared__ float wsum[4][32];
    __shared__ float wvar[4][32];
    int t = threadIdx.x;
    int m0 = blockIdx.x * 32;
    int w = t >> 6, lane = t & 63;
    int li = lane & 15, quad = lane >> 4;

    floatx4 acc[2][4];  // [mi][nf]
#pragma unroll
    for (int mi = 0; mi < 2; mi++)
#pragma unroll
        for (int nf = 0; nf < 4; nf++) acc[mi][nf] = (floatx4){0.f, 0.f, 0.f, 0.f};

    int r0 = m0 + li;      if (r0 > N_ - 1) r0 = N_ - 1;
    int r1 = m0 + 16 + li; if (r1 > N_ - 1) r1 = N_ - 1;
    const u16* A0 = agg + (size_t)r0 * DD;
    const u16* A1 = agg + (size_t)r1 * DD;
    const u16* B0 = Wt + (size_t)(768 + w * 64 + li) * DD;

#pragma unroll 2
    for (int kk = 0; kk < 8; kk++) {
        int ko = kk * 32 + quad * 8;
        short8 a0 = *(const short8*)&A0[ko];
        short8 a1 = *(const short8*)&A1[ko];
        short8 b0 = *(const short8*)&B0[ko];
        short8 b1 = *(const short8*)&B0[16 * DD + ko];
        short8 bb2 = *(const short8*)&B0[32 * DD + ko];
        short8 b3 = *(const short8*)&B0[48 * DD + ko];
        acc[0][0] = __builtin_amdgcn_mfma_f32_16x16x32_bf16(a0, b0, acc[0][0], 0, 0, 0);
        acc[0][1] = __builtin_amdgcn_mfma_f32_16x16x32_bf16(a0, b1, acc[0][1], 0, 0, 0);
        acc[0][2] = __builtin_amdgcn_mfma_f32_16x16x32_bf16(a0, bb2, acc[0][2], 0, 0, 0);
        acc[0][3] = __builtin_amdgcn_mfma_f32_16x16x32_bf16(a0, b3, acc[0][3], 0, 0, 0);
        acc[1][0] = __builtin_amdgcn_mfma_f32_16x16x32_bf16(a1, b0, acc[1][0], 0, 0, 0);
        acc[1][1] = __builtin_amdgcn_mfma_f32_16x16x32_bf16(a1, b1, acc[1][1], 0, 0, 0);
        acc[1][2] = __builtin_amdgcn_mfma_f32_16x16x32_bf16(a1, bb2, acc[1][2], 0, 0, 0);
        acc[1][3] = __builtin_amdgcn_mfma_f32_16x16x32_bf16(a1, b3, acc[1][3], 0, 0, 0);
    }

    // bias
#pragma unroll
    for (int nf = 0; nf < 4; nf++) {
        float bb = bo[w * 64 + nf * 16 + li];
#pragma unroll
        for (int mi = 0; mi < 2; mi++)
#pragma unroll
            for (int r = 0; r < 4; r++) acc[mi][nf][r] += bb;
    }

    // LN2: per-row sum over this wave's 64 cols, then cross-wave via LDS
#pragma unroll
    for (int mi = 0; mi < 2; mi++) {
#pragma unroll
        for (int r = 0; r < 4; r++) {
            float s = acc[mi][0][r] + acc[mi][1][r] + acc[mi][2][r] + acc[mi][3][r];
            s += __shfl_xor(s, 1); s += __shfl_xor(s, 2);
            s += __shfl_xor(s, 4); s += __shfl_xor(s, 8);
            if (li == 0) wsum[w][mi * 16 + quad * 4 + r] = s;
        }
    }
    __syncthreads();
    float mean[2][4];
#pragma unroll
    for (int mi = 0; mi < 2; mi++)
#pragma unroll
        for (int r = 0; r < 4; r++) {
            int rl = mi * 16 + quad * 4 + r;
            mean[mi][r] = (wsum[0][rl] + wsum[1][rl] + wsum[2][rl] + wsum[3][rl]) * (1.f / DD);
        }
#pragma unroll
    for (int mi = 0; mi < 2; mi++) {
#pragma unroll
        for (int r = 0; r < 4; r++) {
            float mm = mean[mi][r];
            float vs = 0.f;
#pragma unroll
            for (int nf = 0; nf < 4; nf++) {
                float d = acc[mi][nf][r] - mm;
                vs += d * d;
            }
            vs += __shfl_xor(vs, 1); vs += __shfl_xor(vs, 2);
            vs += __shfl_xor(vs, 4); vs += __shfl_xor(vs, 8);
            if (li == 0) wvar[w][mi * 16 + quad * 4 + r] = vs;
        }
    }
    __syncthreads();
    float rstd[2][4];
#pragma unroll
    for (int mi = 0; mi < 2; mi++)
#pragma unroll
        for (int r = 0; r < 4; r++) {
            int rl = mi * 16 + quad * 4 + r;
            rstd[mi][r] = rsqrtf((wvar[0][rl] + wvar[1][rl] + wvar[2][rl] + wvar[3][rl]) * (1.f / DD) + LN_EPS);
        }

#pragma unroll
    for (int nf = 0; nf < 4; nf++) {
        int col = w * 64 + nf * 16 + li;
        float gv = g2[col], bv2 = b2[col];
#pragma unroll
        for (int mi = 0; mi < 2; mi++) {
#pragma unroll
            for (int r = 0; r < 4; r++) {
                int row = m0 + mi * 16 + quad * 4 + r;
                if (row >= N_) continue;
                float y = (acc[mi][nf][r] - mean[mi][r]) * rstd[mi][r] * gv + bv2;
                y = fmaxf(y, 0.f);
                out[(size_t)row * DD + col] = x[(size_t)row * DD + col] + y;
            }
        }
    }
}

// ---------------- launch ----------------

extern "C" void kernel_launch(void* const* d_in, const int* in_sizes, int n_in,
                              void* d_out, int out_size, void* d_ws, size_t ws_size,
                              hipStream_t stream) {
    const float* x  = (const float*)d_in[0];
    const int*   ei = (const int*)d_in[1];
    const float* g1 = (const float*)d_in[2];
    const float* b1 = (const float*)d_in[3];
    const float* g2 = (const float*)d_in[4];
    const float* b2 = (const float*)d_in[5];
    const float* Wq = (const float*)d_in[6];
    const float* bq = (const float*)d_in[7];
    const float* Wk = (const float*)d_in[8];
    const float* bk = (const float*)d_in[9];
    const float* Wv = (const float*)d_in[10];
    const float* bv = (const float*)d_in[11];
    const float* Wo = (const float*)d_in[12];
    const float* bo = (const float*)d_in[13];
    float* out = (float*)d_out;

    int N_ = in_sizes[0] / DD;
    int E_ = in_sizes[1] / 2;
    const int* srcp = ei;
    const int* dstp = ei + E_;

    char* w = (char*)d_ws;
    float* q   = (float*)w;  w += (size_t)N_ * DD * 4;
    u16* xn    = (u16*)w;    w += (size_t)N_ * DD * 2;
    u16* kv    = (u16*)w;    w += (size_t)N_ * 512 * 2;
    u16* agg   = (u16*)w;    w += (size_t)N_ * DD * 2;
    u16* Wt    = (u16*)w;    w += (size_t)1024 * DD * 2;
    int* deg    = (int*)w;   w += (size_t)N_ * 4;
    int* offs   = (int*)w;   w += (size_t)(N_ + 1) * 4;
    int* cursor = (int*)w;   w += (size_t)N_ * 4;
    int* csr    = (int*)w;   w += (size_t)E_ * 4;

    k_zero<<<(N_ + 255) / 256, 256, 0, stream>>>(deg, N_);
    k_count<<<(E_ + 255) / 256, 256, 0, stream>>>(dstp, E_, deg);
    k_scan<<<1, 1024, 0, stream>>>(deg, N_, offs, cursor);
    k_fill<<<(E_ + 255) / 256, 256, 0, stream>>>(srcp, dstp, E_, offs, cursor, csr);
    k_prep<<<dim3(4, 16), 256, 0, stream>>>(Wq, Wk, Wv, Wo, Wt);
    k_ln1<<<(N_ + 3) / 4, 256, 0, stream>>>(x, g1, b1, N_, xn);
    k_qkv<<<dim3((N_ + 127) / 128, 6), 256, 0, stream>>>(xn, Wt, bq, bk, bv, N_, q, kv);
    k_attn<<<N_, 256, 0, stream>>>(q, kv, offs, csr, agg);
    k_out<<<(N_ + 31) / 32, 256, 0, stream>>>(agg, Wt, bo, g2, b2, x, N_, out);
}